// Round 6
// baseline (915.085 us; speedup 1.0000x reference)
//
#include <hip/hip_runtime.h>
#include <hip/hip_bf16.h>
#include <math.h>

#define NN 2
#define CC 512
#define PP 6272            // T*H*W
#define TCH 896            // t-chunk rows (7 chunks x 7 tiles of 128)
#define NCHK 7
#define NJT 49             // PP/128 j-tiles per energy row
#define KSP 7              // k_me s-split (each 896 = 14 x 64)
static const size_t PPC = (size_t)PP * CC;   // per-n projection elems
static const size_t NCP = (size_t)NN * PPC;  // 6,422,528

typedef unsigned short ushortT;
typedef __attribute__((ext_vector_type(8))) short short8;   // 8 bf16 = 4 VGPR
typedef __attribute__((ext_vector_type(4))) float f32x4;

__device__ __forceinline__ ushortT f2bf(float f) {
  __hip_bfloat16 h = __float2bfloat16(f);
  return *reinterpret_cast<ushortT*>(&h);
}
__device__ __forceinline__ float bf2f(ushortT u) {
  return __uint_as_float(((unsigned)u) << 16);
}

// async global->LDS, 16B/lane. LDS dest = wave-uniform base + lane*16.
__device__ __forceinline__ void ld_g2l(const void* g, void* l) {
  __builtin_amdgcn_global_load_lds(
      (const __attribute__((address_space(1))) void*)g,
      (__attribute__((address_space(3))) void*)l, 16, 0, 0);
}

// exp((e - m)) * rz applied elementwise to a bf16x8 fragment
__device__ __forceinline__ short8 exp_frag(short8 v, float m, float rz) {
  short8 o;
#pragma unroll
  for (int j = 0; j < 8; ++j)
    o[j] = (short)f2bf(__expf(bf2f((ushortT)v[j]) - m) * rz);
  return o;
}

// ---------------------------------------------------------------------------
// fused fp32 -> bf16 cast for the four 512x512 weights (grid.y picks matrix)
// ---------------------------------------------------------------------------
__global__ __launch_bounds__(256) void k_cast4(const float* __restrict__ W0,
                                               const float* __restrict__ W1,
                                               const float* __restrict__ W2,
                                               const float* __restrict__ W3,
                                               ushortT* __restrict__ dst) {
  const float* src = (blockIdx.y == 0) ? W0 : (blockIdx.y == 1) ? W1
                    : (blockIdx.y == 2) ? W2 : W3;
  const int i = (blockIdx.x * 256 + threadIdx.x) * 4;
  float4 v = *(const float4*)&src[i];
  ushort4 o;
  o.x = f2bf(v.x); o.y = f2bf(v.y); o.z = f2bf(v.z); o.w = f2bf(v.w);
  *(ushort4*)&dst[(size_t)blockIdx.y * CC * CC + i] = o;
}

// ---------------------------------------------------------------------------
// transpose-cast: fp32 [n][c][p] -> bf16 [n][p][c]
// ---------------------------------------------------------------------------
__global__ void k_castT(const float* __restrict__ in, ushortT* __restrict__ out) {
  __shared__ float T[32][33];
  const int p0 = blockIdx.x * 32, c0 = blockIdx.y * 32;
  const int tx = threadIdx.x, ty = threadIdx.y;
  const size_t nbi = (size_t)blockIdx.z * PPC;
#pragma unroll
  for (int i = 0; i < 4; ++i)
    T[ty + i * 8][tx] = in[nbi + (size_t)(c0 + ty + i * 8) * PP + p0 + tx];
  __syncthreads();
#pragma unroll
  for (int i = 0; i < 4; ++i) {
    int r = ty + i * 8;
    out[nbi + (size_t)(p0 + r) * CC + c0 + tx] = f2bf(T[tx][r]);
  }
}

// ---------------------------------------------------------------------------
// BT-GEMM (convs): D[i,j] = sum_k A[i,k]*B[j,k] + bias, 128x128, BK=64.
// OM 0: bf16 out, bias[j] | OM 1: bf16 out, bias[i]
// ---------------------------------------------------------------------------
template <int OM>
__global__ __launch_bounds__(256) void k_bgemm(const ushortT* __restrict__ A,
                                               const ushortT* __restrict__ B,
                                               const float* __restrict__ bias,
                                               ushortT* __restrict__ out,
                                               int KD, size_t sAn, size_t sBn,
                                               size_t sOn, int ldo) {
  __shared__ __align__(16) ushortT At[128 * 64];
  __shared__ __align__(16) ushortT Bt[128 * 64];
  const int tid = threadIdx.x;
  const int l = tid & 63, w = tid >> 6;
  const int j0 = blockIdx.x * 128;
  const int i0 = blockIdx.y * 128;
  A += (size_t)blockIdx.z * sAn;
  B += (size_t)blockIdx.z * sBn;
  out += (size_t)blockIdx.z * sOn;
  const int wi = (w & 1) * 64, wj = (w >> 1) * 64;
  const int lr = l & 15, lk = l >> 4;
  const int sr = l >> 3, scg = l & 7;

  f32x4 acc[4][4] = {};

  for (int k0 = 0; k0 < KD; k0 += 64) {
#pragma unroll
    for (int i = 0; i < 4; ++i) {
      int row = w * 32 + i * 8 + sr;
      int cs = scg ^ (row & 7);
      ld_g2l(A + (size_t)(i0 + row) * KD + k0 + cs * 8, (char*)At + (w * 4 + i) * 1024);
      ld_g2l(B + (size_t)(j0 + row) * KD + k0 + cs * 8, (char*)Bt + (w * 4 + i) * 1024);
    }
    __syncthreads();
#pragma unroll
    for (int ks = 0; ks < 2; ++ks) {
      short8 af[4], bfv[4];
      const int cc = ks * 4 + lk;
#pragma unroll
      for (int tt = 0; tt < 4; ++tt) {
        int row = wi + tt * 16 + lr;
        af[tt] = *(const short8*)((const char*)At + row * 128 + ((cc ^ (row & 7)) * 16));
      }
#pragma unroll
      for (int ss = 0; ss < 4; ++ss) {
        int row = wj + ss * 16 + lr;
        bfv[ss] = *(const short8*)((const char*)Bt + row * 128 + ((cc ^ (row & 7)) * 16));
      }
#pragma unroll
      for (int tt = 0; tt < 4; ++tt)
#pragma unroll
        for (int ss = 0; ss < 4; ++ss)
          acc[tt][ss] = __builtin_amdgcn_mfma_f32_16x16x32_bf16(af[tt], bfv[ss], acc[tt][ss], 0, 0, 0);
    }
    __syncthreads();
  }
  const int r4 = (l >> 4) * 4;
  if (OM == 0) {
    float bj[4];
#pragma unroll
    for (int ss = 0; ss < 4; ++ss) bj[ss] = bias[j0 + wj + ss * 16 + lr];
#pragma unroll
    for (int tt = 0; tt < 4; ++tt)
#pragma unroll
      for (int r = 0; r < 4; ++r) {
        int i = i0 + wi + tt * 16 + r4 + r;
#pragma unroll
        for (int ss = 0; ss < 4; ++ss) {
          int j = j0 + wj + ss * 16 + lr;
          out[(size_t)i * ldo + j] = f2bf(acc[tt][ss][r] + bj[ss]);
        }
      }
  } else {
#pragma unroll
    for (int tt = 0; tt < 4; ++tt)
#pragma unroll
      for (int r = 0; r < 4; ++r) {
        int i = i0 + wi + tt * 16 + r4 + r;
        float bi = bias[i];
#pragma unroll
        for (int ss = 0; ss < 4; ++ss) {
          int j = j0 + wj + ss * 16 + lr;
          out[(size_t)i * ldo + j] = f2bf(acc[tt][ss][r] + bi);
        }
      }
  }
}

// ---------------------------------------------------------------------------
// Energy GEMM (bf16 E out) + fused partial softmax stats.
// grid (NJT, TCH/128, NN).
// ---------------------------------------------------------------------------
__global__ __launch_bounds__(256) void k_energy(const ushortT* __restrict__ phxT,
                                                const ushortT* __restrict__ pgT,
                                                ushortT* __restrict__ Ech,
                                                float* __restrict__ Estat,
                                                int tbase) {
  __shared__ __align__(16) ushortT At[128 * 64];
  __shared__ __align__(16) ushortT Bt[128 * 64];
  __shared__ float Sm[128][2], Ss[128][2];
  const int tid = threadIdx.x;
  const int l = tid & 63, w = tid >> 6;
  const int j0 = blockIdx.x * 128;
  const int i0 = blockIdx.y * 128;                 // within chunk
  const int z = blockIdx.z;
  const ushortT* A = phxT + (size_t)z * PPC + (size_t)tbase * CC;
  const ushortT* B = pgT + (size_t)z * PPC;
  ushortT* out = Ech + (size_t)z * TCH * PP;
  const int wi = (w & 1) * 64, wj = (w >> 1) * 64;
  const int lr = l & 15, lk = l >> 4;
  const int sr = l >> 3, scg = l & 7;

  f32x4 acc[4][4] = {};

  for (int k0 = 0; k0 < CC; k0 += 64) {
#pragma unroll
    for (int i = 0; i < 4; ++i) {
      int row = w * 32 + i * 8 + sr;
      int cs = scg ^ (row & 7);
      ld_g2l(A + (size_t)(i0 + row) * CC + k0 + cs * 8, (char*)At + (w * 4 + i) * 1024);
      ld_g2l(B + (size_t)(j0 + row) * CC + k0 + cs * 8, (char*)Bt + (w * 4 + i) * 1024);
    }
    __syncthreads();
#pragma unroll
    for (int ks = 0; ks < 2; ++ks) {
      short8 af[4], bfv[4];
      const int cc = ks * 4 + lk;
#pragma unroll
      for (int tt = 0; tt < 4; ++tt) {
        int row = wi + tt * 16 + lr;
        af[tt] = *(const short8*)((const char*)At + row * 128 + ((cc ^ (row & 7)) * 16));
      }
#pragma unroll
      for (int ss = 0; ss < 4; ++ss) {
        int row = wj + ss * 16 + lr;
        bfv[ss] = *(const short8*)((const char*)Bt + row * 128 + ((cc ^ (row & 7)) * 16));
      }
#pragma unroll
      for (int tt = 0; tt < 4; ++tt)
#pragma unroll
        for (int ss = 0; ss < 4; ++ss)
          acc[tt][ss] = __builtin_amdgcn_mfma_f32_16x16x32_bf16(af[tt], bfv[ss], acc[tt][ss], 0, 0, 0);
    }
    __syncthreads();
  }
  const int r4 = (l >> 4) * 4;
  // E write (bf16, raw logits)
#pragma unroll
  for (int tt = 0; tt < 4; ++tt)
#pragma unroll
    for (int r = 0; r < 4; ++r) {
      int i = i0 + wi + tt * 16 + r4 + r;
#pragma unroll
      for (int ss = 0; ss < 4; ++ss) {
        int j = j0 + wj + ss * 16 + lr;
        out[(size_t)i * PP + j] = f2bf(acc[tt][ss][r]);
      }
    }
  // per-row partial stats over this block's 128 cols
  const int jh = w >> 1;
  const int rbase = (w & 1) * 64;
#pragma unroll
  for (int tt = 0; tt < 4; ++tt)
#pragma unroll
    for (int r = 0; r < 4; ++r) {
      float mx = fmaxf(fmaxf(acc[tt][0][r], acc[tt][1][r]),
                       fmaxf(acc[tt][2][r], acc[tt][3][r]));
#pragma unroll
      for (int d = 1; d < 16; d <<= 1) mx = fmaxf(mx, __shfl_xor(mx, d));
      float sx = __expf(acc[tt][0][r] - mx) + __expf(acc[tt][1][r] - mx) +
                 __expf(acc[tt][2][r] - mx) + __expf(acc[tt][3][r] - mx);
#pragma unroll
      for (int d = 1; d < 16; d <<= 1) sx += __shfl_xor(sx, d);
      if (lr == 0) {
        int row = rbase + tt * 16 + r4 + r;
        Sm[row][jh] = mx;
        Ss[row][jh] = sx;
      }
    }
  __syncthreads();
  if (tid < 128) {
    float m0 = Sm[tid][0], m1 = Sm[tid][1];
    float m = fmaxf(m0, m1);
    float s = Ss[tid][0] * __expf(m0 - m) + Ss[tid][1] * __expf(m1 - m);
    size_t o = (((size_t)z * TCH + i0 + tid) * NJT + blockIdx.x) * 2;
    Estat[o] = m;
    Estat[o + 1] = s;
  }
}

// ---------------------------------------------------------------------------
// combine NJT partial stats per row -> rowMZ (m, 1/Z).  NN*TCH rows.
// ---------------------------------------------------------------------------
__global__ __launch_bounds__(256) void k_combine(const float* __restrict__ Estat,
                                                 float* __restrict__ rowMZ) {
  const int gid = blockIdx.x * 256 + threadIdx.x;   // 0..NN*TCH-1
  const float* p = Estat + (size_t)gid * NJT * 2;
  float m = -INFINITY;
#pragma unroll 7
  for (int j = 0; j < NJT; ++j) m = fmaxf(m, p[j * 2]);
  float zz = 0.f;
#pragma unroll 7
  for (int j = 0; j < NJT; ++j) zz += p[j * 2 + 1] * __expf(p[j * 2] - m);
  rowMZ[gid * 2] = m;
  rowMZ[gid * 2 + 1] = 1.0f / zz;
}

// ---------------------------------------------------------------------------
// me partial with fused exp: mePart[ks][z][c][tl] (bf16)
//   = sum_{s in ks-range} phm[c,s] * exp(E[tl,s]-m_tl)/Z_tl
// 128c x 64t tile, BK=64. grid (TCH/64, CC/128, NN*KSP).
// ---------------------------------------------------------------------------
__global__ __launch_bounds__(256) void k_me(const ushortT* __restrict__ phmB,
                                            const ushortT* __restrict__ Ech,
                                            const float* __restrict__ rowMZ,
                                            ushortT* __restrict__ mePart) {
  __shared__ __align__(16) ushortT At[128 * 64];   // phm [c][k]
  __shared__ __align__(16) ushortT Bt[64 * 64];    // E   [t][k]
  const int tid = threadIdx.x;
  const int l = tid & 63, w = tid >> 6;
  const int tl0 = blockIdx.x * 64;
  const int c0 = blockIdx.y * 128;
  const int bz = blockIdx.z;
  const int z = bz / KSP, ks = bz % KSP;
  const size_t nb = (size_t)z * PPC;
  const ushortT* Eb = Ech + (size_t)z * TCH * PP;
  const int wc = (w & 1) * 64, wt = (w >> 1) * 32;
  const int lr = l & 15, lk = l >> 4;
  const int sr = l >> 3, scg = l & 7;

  // per-lane row softmax constants (fixed rows across the whole K loop)
  float mt[2], rzt[2];
#pragma unroll
  for (int tt = 0; tt < 2; ++tt) {
    int t = tl0 + wt + tt * 16 + lr;
    mt[tt] = rowMZ[((size_t)z * TCH + t) * 2];
    rzt[tt] = rowMZ[((size_t)z * TCH + t) * 2 + 1];
  }

  f32x4 acc[4][2] = {};

  const int sBeg = ks * (PP / KSP);        // 896 each
  const int sEnd = sBeg + PP / KSP;
  for (int s0 = sBeg; s0 < sEnd; s0 += 64) {
#pragma unroll
    for (int i = 0; i < 4; ++i) {
      int row = w * 32 + i * 8 + sr;
      int cs = scg ^ (row & 7);
      ld_g2l(phmB + nb + (size_t)(c0 + row) * PP + s0 + cs * 8,
             (char*)At + (w * 4 + i) * 1024);
    }
#pragma unroll
    for (int i = 0; i < 2; ++i) {
      int row = w * 16 + i * 8 + sr;
      int cs = scg ^ (row & 7);
      ld_g2l(Eb + (size_t)(tl0 + row) * PP + s0 + cs * 8,
             (char*)Bt + (w * 2 + i) * 1024);
    }
    __syncthreads();
#pragma unroll
    for (int kk = 0; kk < 2; ++kk) {
      short8 af[4], bfv[2];
      const int cc = kk * 4 + lk;
#pragma unroll
      for (int ct = 0; ct < 4; ++ct) {
        int row = wc + ct * 16 + lr;
        af[ct] = *(const short8*)((const char*)At + row * 128 + ((cc ^ (row & 7)) * 16));
      }
#pragma unroll
      for (int tt = 0; tt < 2; ++tt) {
        int row = wt + tt * 16 + lr;
        short8 raw = *(const short8*)((const char*)Bt + row * 128 + ((cc ^ (row & 7)) * 16));
        bfv[tt] = exp_frag(raw, mt[tt], rzt[tt]);
      }
#pragma unroll
      for (int ct = 0; ct < 4; ++ct)
#pragma unroll
        for (int tt = 0; tt < 2; ++tt)
          acc[ct][tt] = __builtin_amdgcn_mfma_f32_16x16x32_bf16(af[ct], bfv[tt], acc[ct][tt], 0, 0, 0);
    }
    __syncthreads();
  }
  const int r4 = (l >> 4) * 4;
  ushortT* out = mePart + ((size_t)(ks * NN + z) * CC) * TCH;
#pragma unroll
  for (int ct = 0; ct < 4; ++ct)
#pragma unroll
    for (int tt = 0; tt < 2; ++tt)
#pragma unroll
      for (int r = 0; r < 4; ++r) {
        int c = c0 + wc + ct * 16 + r4 + r;
        int tl = tl0 + wt + tt * 16 + lr;
        out[(size_t)c * TCH + tl] = f2bf(acc[ct][tt][r]);
      }
}

// ---------------------------------------------------------------------------
// meb[z][c][tbase+tl] (bf16) = sum over KSP partials
// ---------------------------------------------------------------------------
__global__ __launch_bounds__(256) void k_meadd(const ushortT* __restrict__ mePart,
                                               ushortT* __restrict__ meb, int tbase) {
  const int idx = (blockIdx.x * 256 + threadIdx.x) * 4;   // over NN*CC*TCH
  const int tl = idx % TCH;
  const int c = (idx / TCH) % CC;
  const int z = idx / (TCH * CC);
  float s0 = 0.f, s1 = 0.f, s2 = 0.f, s3 = 0.f;
#pragma unroll
  for (int ks = 0; ks < KSP; ++ks) {
    const size_t o = (((size_t)(ks * NN + z) * CC) + c) * TCH + tl;
    ushort4 a = *(const ushort4*)&mePart[o];
    s0 += bf2f(a.x); s1 += bf2f(a.y); s2 += bf2f(a.z); s3 += bf2f(a.w);
  }
  ushort4 v;
  v.x = f2bf(s0); v.y = f2bf(s1); v.z = f2bf(s2); v.w = f2bf(s3);
  *(ushort4*)&meb[((size_t)z * CC + c) * PP + tbase + tl] = v;
}

// ---------------------------------------------------------------------------
// softmax stats of bf16 me rows (per n,c)
// ---------------------------------------------------------------------------
__global__ __launch_bounds__(256) void k_soft2(const ushortT* __restrict__ me,
                                               float* __restrict__ m2,
                                               float* __restrict__ Z2) {
  __shared__ float red[256];
  const ushortT* row = me + (size_t)blockIdx.x * PP;
  const int tid = threadIdx.x;
  const int NCH = PP / 8;
  float m = -INFINITY;
  for (int i = tid; i < NCH; i += 256) {
    short8 v = *(const short8*)&row[i * 8];
#pragma unroll
    for (int j = 0; j < 8; ++j) m = fmaxf(m, bf2f((ushortT)v[j]));
  }
  red[tid] = m;
  __syncthreads();
  for (int s = 128; s > 0; s >>= 1) {
    if (tid < s) red[tid] = fmaxf(red[tid], red[tid + s]);
    __syncthreads();
  }
  m = red[0];
  __syncthreads();
  float zz = 0.f;
  for (int i = tid; i < NCH; i += 256) {
    short8 v = *(const short8*)&row[i * 8];
#pragma unroll
    for (int j = 0; j < 8; ++j) zz += __expf(bf2f((ushortT)v[j]) - m);
  }
  red[tid] = zz;
  __syncthreads();
  for (int s = 128; s > 0; s >>= 1) {
    if (tid < s) red[tid] += red[tid + s];
    __syncthreads();
  }
  if (tid == 0) { m2[blockIdx.x] = m; Z2[blockIdx.x] = red[0]; }
}

// ---------------------------------------------------------------------------
// BatchNorm stats per channel over (N, THW) from bf16 wz
// ---------------------------------------------------------------------------
__global__ __launch_bounds__(256) void k_bnstat(const ushortT* __restrict__ wz,
                                                float* __restrict__ mu,
                                                float* __restrict__ rinv) {
  __shared__ float rs[256];
  __shared__ float rq[256];
  const int c = blockIdx.x;
  const int tid = threadIdx.x;
  const int NCH = PP / 8;
  float s = 0.f, q = 0.f;
  for (int n = 0; n < NN; ++n) {
    const ushortT* rowp = wz + (size_t)n * CC * PP + (size_t)c * PP;
    for (int i = tid; i < NCH; i += 256) {
      short8 v = *(const short8*)&rowp[i * 8];
#pragma unroll
      for (int j = 0; j < 8; ++j) {
        float f = bf2f((ushortT)v[j]);
        s += f;
        q += f * f;
      }
    }
  }
  rs[tid] = s; rq[tid] = q;
  __syncthreads();
  for (int st = 128; st > 0; st >>= 1) {
    if (tid < st) { rs[tid] += rs[tid + st]; rq[tid] += rq[tid + st]; }
    __syncthreads();
  }
  if (tid == 0) {
    const float inv_n = 1.0f / (float)(NN * PP);
    float mean = rs[0] * inv_n;
    float var = rq[0] * inv_n - mean * mean;
    mu[c] = mean;
    rinv[c] = rsqrtf(var + 1e-5f);
  }
}

__global__ __launch_bounds__(256) void k_final(const ushortT* __restrict__ pmB,
                                               const ushortT* __restrict__ me,
                                               const ushortT* __restrict__ wz,
                                               const float* __restrict__ m2,
                                               const float* __restrict__ Z2,
                                               const float* __restrict__ mu,
                                               const float* __restrict__ rinv,
                                               const float* __restrict__ bnw,
                                               const float* __restrict__ bnb,
                                               const float* __restrict__ gamma,
                                               float* __restrict__ out) {
  const int e4 = blockIdx.x * 256 + threadIdx.x;
  const size_t e = (size_t)e4 * 4;
  const int nc = (int)(e / PP);
  const int c = nc & (CC - 1);
  const float m = m2[nc];
  const float rz = 1.0f / Z2[nc];
  const float mub = mu[c];
  const float ri = rinv[c] * bnw[c];
  const float bb = bnb[c];
  const float g = gamma[0];
  ushort4 pv = *(const ushort4*)&pmB[e];
  ushort4 mev = *(const ushort4*)&me[e];
  ushort4 wzv = *(const ushort4*)&wz[e];
  float4 o;
  o.x = g * bf2f(pv.x) * (__expf(bf2f(mev.x) - m) * rz) + (bf2f(wzv.x) - mub) * ri + bb;
  o.y = g * bf2f(pv.y) * (__expf(bf2f(mev.y) - m) * rz) + (bf2f(wzv.y) - mub) * ri + bb;
  o.z = g * bf2f(pv.z) * (__expf(bf2f(mev.z) - m) * rz) + (bf2f(wzv.z) - mub) * ri + bb;
  o.w = g * bf2f(pv.w) * (__expf(bf2f(mev.w) - m) * rz) + (bf2f(wzv.w) - mub) * ri + bb;
  *(float4*)&out[e] = o;
}

// ---------------------------------------------------------------------------
extern "C" void kernel_launch(void* const* d_in, const int* in_sizes, int n_in,
                              void* d_out, int out_size, void* d_ws, size_t ws_size,
                              hipStream_t stream) {
  (void)in_sizes; (void)n_in; (void)out_size; (void)ws_size;
  const float* x    = (const float*)d_in[0];
  const float* mask = (const float*)d_in[1];
  const float* Wh   = (const float*)d_in[2];
  const float* bh   = (const float*)d_in[3];
  const float* Wg   = (const float*)d_in[4];
  const float* bg   = (const float*)d_in[5];
  const float* Wm   = (const float*)d_in[6];
  const float* bm   = (const float*)d_in[7];
  const float* Wz   = (const float*)d_in[8];
  const float* bz   = (const float*)d_in[9];
  const float* bnw  = (const float*)d_in[10];
  const float* bnb  = (const float*)d_in[11];
  const float* gam  = (const float*)d_in[12];

  // ---- workspace layout (~144 MB) ----
  ushortT* wzb  = (ushortT*)d_ws;                // bf16 [n][c][p]
  ushortT* meb  = wzb + NCP;                     // bf16 [n][c][t]
  ushortT* pmB  = meb + NCP;                     // bf16 [n][c][p]
  ushortT* phxT = pmB + NCP;                     // bf16 [n][t][c]
  ushortT* pgT  = phxT + NCP;                    // bf16 [n][s][c]
  ushortT* phmB = pgT + NCP;                     // bf16 [n][c][s]
  ushortT* Wbf  = phmB + NCP;                    // 4 x 512x512 bf16
  ushortT* Whbf = Wbf;
  ushortT* Wgbf = Wbf + 1 * CC * CC;
  ushortT* Wmbf = Wbf + 2 * CC * CC;
  ushortT* Wzbf = Wbf + 3 * CC * CC;
  float* m2    = (float*)(Wbf + 4 * CC * CC);
  float* Z2    = m2 + NN * CC;
  float* mu    = Z2 + NN * CC;
  float* rin   = mu + CC;
  float* rowMZ = rin + CC;                       // NN*TCH*2
  float* Estat = rowMZ + NN * TCH * 2;           // NN*TCH*NJT*2  ~0.7 MB
  float* region = Estat + (size_t)NN * TCH * NJT * 2 + 4;
  ushortT* xT    = (ushortT*)region;             // overlay (conv phase) 25.7 MB
  ushortT* maskT = xT + NCP;
  ushortT* Ech    = (ushortT*)region;            // bf16 [n][TCH][PP]  22.5 MB
  ushortT* mePart = Ech + (size_t)NN * TCH * PP; // bf16 [KSP][n][c][TCH] 12.85 MB

  // ---- casts ----
  k_cast4<<<dim3(256, 4), 256, 0, stream>>>(Wh, Wg, Wm, Wz, Wbf);
  dim3 gct(PP / 32, CC / 32, NN);
  k_castT<<<gct, dim3(32, 8), 0, stream>>>(x, xT);
  k_castT<<<gct, dim3(32, 8), 0, stream>>>(mask, maskT);

  // ---- 1x1 convs as MFMA BT-GEMMs ----
  dim3 gPc(CC / 128, PP / 128, NN);   // out [p][co]
  k_bgemm<0><<<gPc, 256, 0, stream>>>(xT, Whbf, bh, phxT, CC, PPC, 0, PPC, CC);
  k_bgemm<0><<<gPc, 256, 0, stream>>>(xT, Wgbf, bg, pgT, CC, PPC, 0, PPC, CC);
  dim3 gCp(PP / 128, CC / 128, NN);   // out [co][p]
  k_bgemm<1><<<gCp, 256, 0, stream>>>(Whbf, maskT, bh, phmB, CC, 0, PPC, PPC, PP);
  k_bgemm<1><<<gCp, 256, 0, stream>>>(Wmbf, xT, bm, pmB, CC, 0, PPC, PPC, PP);
  k_bgemm<1><<<gCp, 256, 0, stream>>>(Wzbf, xT, bz, wzb, CC, 0, PPC, PPC, PP);

  // ---- attention: chunked energy(+stats) -> combine -> me(fused exp) -> add
  for (int ch = 0; ch < NCHK; ++ch) {
    const int tbase = ch * TCH;
    dim3 gE(NJT, TCH / 128, NN);
    k_energy<<<gE, 256, 0, stream>>>(phxT, pgT, Ech, Estat, tbase);
    k_combine<<<NN * TCH / 256, 256, 0, stream>>>(Estat, rowMZ);
    dim3 gM(TCH / 64, CC / 128, NN * KSP);
    k_me<<<gM, 256, 0, stream>>>(phmB, Ech, rowMZ, mePart);
    k_meadd<<<NN * CC * TCH / 1024, 256, 0, stream>>>(mePart, meb, tbase);
  }

  // ---- tails ----
  k_soft2<<<NN * CC, 256, 0, stream>>>(meb, m2, Z2);
  k_bnstat<<<CC, 256, 0, stream>>>(wzb, mu, rin);
  const int total4 = (int)(NCP / 4);
  k_final<<<total4 / 256, 256, 0, stream>>>(pmB, meb, wzb, m2, Z2, mu, rin,
                                            bnw, bnb, gam, (float*)d_out);
}

// Round 7
// 844.299 us; speedup vs baseline: 1.0838x; 1.0838x over previous
//
#include <hip/hip_runtime.h>
#include <hip/hip_bf16.h>
#include <math.h>

#define NN 2
#define CC 512
#define PP 6272            // T*H*W
#define TCH 896            // t-chunk rows (7 chunks x 7 tiles of 128)
#define NCHK 7
#define NJT 49             // PP/128 j-tiles per energy row
#define KSP 7              // k_me s-split (each 896 = 14 x 64)
static const size_t PPC = (size_t)PP * CC;   // per-n projection elems
static const size_t NCP = (size_t)NN * PPC;  // 6,422,528

typedef unsigned short ushortT;
typedef __attribute__((ext_vector_type(8))) short short8;   // 8 bf16 = 4 VGPR
typedef __attribute__((ext_vector_type(4))) float f32x4;

__device__ __forceinline__ ushortT f2bf(float f) {
  __hip_bfloat16 h = __float2bfloat16(f);
  return *reinterpret_cast<ushortT*>(&h);
}
__device__ __forceinline__ float bf2f(ushortT u) {
  return __uint_as_float(((unsigned)u) << 16);
}

// async global->LDS, 16B/lane. LDS dest = wave-uniform base + lane*16.
__device__ __forceinline__ void ld_g2l(const void* g, void* l) {
  __builtin_amdgcn_global_load_lds(
      (const __attribute__((address_space(1))) void*)g,
      (__attribute__((address_space(3))) void*)l, 16, 0, 0);
}

// ---------------------------------------------------------------------------
// fused fp32 -> bf16 cast for the four 512x512 weights (grid.y picks matrix)
// ---------------------------------------------------------------------------
__global__ __launch_bounds__(256) void k_cast4(const float* __restrict__ W0,
                                               const float* __restrict__ W1,
                                               const float* __restrict__ W2,
                                               const float* __restrict__ W3,
                                               ushortT* __restrict__ dst) {
  const float* src = (blockIdx.y == 0) ? W0 : (blockIdx.y == 1) ? W1
                    : (blockIdx.y == 2) ? W2 : W3;
  const int i = (blockIdx.x * 256 + threadIdx.x) * 4;
  float4 v = *(const float4*)&src[i];
  ushort4 o;
  o.x = f2bf(v.x); o.y = f2bf(v.y); o.z = f2bf(v.z); o.w = f2bf(v.w);
  *(ushort4*)&dst[(size_t)blockIdx.y * CC * CC + i] = o;
}

// ---------------------------------------------------------------------------
// transpose-cast: fp32 [n][c][p] -> bf16 [n][p][c]
// ---------------------------------------------------------------------------
__global__ void k_castT(const float* __restrict__ in, ushortT* __restrict__ out) {
  __shared__ float T[32][33];
  const int p0 = blockIdx.x * 32, c0 = blockIdx.y * 32;
  const int tx = threadIdx.x, ty = threadIdx.y;
  const size_t nbi = (size_t)blockIdx.z * PPC;
#pragma unroll
  for (int i = 0; i < 4; ++i)
    T[ty + i * 8][tx] = in[nbi + (size_t)(c0 + ty + i * 8) * PP + p0 + tx];
  __syncthreads();
#pragma unroll
  for (int i = 0; i < 4; ++i) {
    int r = ty + i * 8;
    out[nbi + (size_t)(p0 + r) * CC + c0 + tx] = f2bf(T[tx][r]);
  }
}

// ---------------------------------------------------------------------------
// BT-GEMM (convs): D[i,j] = sum_k A[i,k]*B[j,k] + bias, 128x128, BK=64.
// OM 0: bf16 out, bias[j] | OM 1: bf16 out, bias[i]
// Epilogue: LDS transpose -> coalesced 16B stores.
// ---------------------------------------------------------------------------
template <int OM>
__global__ __launch_bounds__(256) void k_bgemm(const ushortT* __restrict__ A,
                                               const ushortT* __restrict__ B,
                                               const float* __restrict__ bias,
                                               ushortT* __restrict__ out,
                                               int KD, size_t sAn, size_t sBn,
                                               size_t sOn, int ldo) {
  __shared__ __align__(16) ushortT smem[17408];   // staging 32KB, epi 128x136
  ushortT* At = smem;
  ushortT* Bt = smem + 8192;
  const int tid = threadIdx.x;
  const int l = tid & 63, w = tid >> 6;
  const int j0 = blockIdx.x * 128;
  const int i0 = blockIdx.y * 128;
  A += (size_t)blockIdx.z * sAn;
  B += (size_t)blockIdx.z * sBn;
  out += (size_t)blockIdx.z * sOn;
  const int wi = (w & 1) * 64, wj = (w >> 1) * 64;
  const int lr = l & 15, lk = l >> 4;
  const int sr = l >> 3, scg = l & 7;

  f32x4 acc[4][4] = {};

  for (int k0 = 0; k0 < KD; k0 += 64) {
#pragma unroll
    for (int i = 0; i < 4; ++i) {
      int row = w * 32 + i * 8 + sr;
      int cs = scg ^ (row & 7);
      ld_g2l(A + (size_t)(i0 + row) * KD + k0 + cs * 8, (char*)At + (w * 4 + i) * 1024);
      ld_g2l(B + (size_t)(j0 + row) * KD + k0 + cs * 8, (char*)Bt + (w * 4 + i) * 1024);
    }
    __syncthreads();
#pragma unroll
    for (int ks = 0; ks < 2; ++ks) {
      short8 af[4], bfv[4];
      const int cc = ks * 4 + lk;
#pragma unroll
      for (int tt = 0; tt < 4; ++tt) {
        int row = wi + tt * 16 + lr;
        af[tt] = *(const short8*)((const char*)At + row * 128 + ((cc ^ (row & 7)) * 16));
      }
#pragma unroll
      for (int ss = 0; ss < 4; ++ss) {
        int row = wj + ss * 16 + lr;
        bfv[ss] = *(const short8*)((const char*)Bt + row * 128 + ((cc ^ (row & 7)) * 16));
      }
#pragma unroll
      for (int tt = 0; tt < 4; ++tt)
#pragma unroll
        for (int ss = 0; ss < 4; ++ss)
          acc[tt][ss] = __builtin_amdgcn_mfma_f32_16x16x32_bf16(af[tt], bfv[ss], acc[tt][ss], 0, 0, 0);
    }
    __syncthreads();
  }
  const int r4 = (l >> 4) * 4;
  ushortT (*Tr)[136] = (ushortT(*)[136])smem;
  if (OM == 0) {
    float bj[4];
#pragma unroll
    for (int ss = 0; ss < 4; ++ss) bj[ss] = bias[j0 + wj + ss * 16 + lr];
#pragma unroll
    for (int tt = 0; tt < 4; ++tt)
#pragma unroll
      for (int r = 0; r < 4; ++r) {
        int row = wi + tt * 16 + r4 + r;
#pragma unroll
        for (int ss = 0; ss < 4; ++ss)
          Tr[row][wj + ss * 16 + lr] = f2bf(acc[tt][ss][r] + bj[ss]);
      }
  } else {
#pragma unroll
    for (int tt = 0; tt < 4; ++tt)
#pragma unroll
      for (int r = 0; r < 4; ++r) {
        int row = wi + tt * 16 + r4 + r;
        float bi = bias[i0 + row];
#pragma unroll
        for (int ss = 0; ss < 4; ++ss)
          Tr[row][wj + ss * 16 + lr] = f2bf(acc[tt][ss][r] + bi);
      }
  }
  __syncthreads();
#pragma unroll
  for (int q = 0; q < 8; ++q) {
    int chunk = q * 256 + tid;       // 2048 chunks of 8 ushorts
    int row = chunk >> 4, cg = chunk & 15;
    short8 v = *(const short8*)&Tr[row][cg * 8];
    *(short8*)&out[(size_t)(i0 + row) * ldo + j0 + cg * 8] = v;
  }
}

// ---------------------------------------------------------------------------
// Energy GEMM (bf16 E out) + fused partial softmax stats.
// Epilogue: stats via shuffles, then LDS-transpose coalesced E store.
// grid (NJT, TCH/128, NN).
// ---------------------------------------------------------------------------
__global__ __launch_bounds__(256) void k_energy(const ushortT* __restrict__ phxT,
                                                const ushortT* __restrict__ pgT,
                                                ushortT* __restrict__ Ech,
                                                float* __restrict__ Estat,
                                                int tbase) {
  __shared__ __align__(16) ushortT smem[17408];
  __shared__ float Sm[128][2], Ss[128][2];
  ushortT* At = smem;
  ushortT* Bt = smem + 8192;
  const int tid = threadIdx.x;
  const int l = tid & 63, w = tid >> 6;
  const int j0 = blockIdx.x * 128;
  const int i0 = blockIdx.y * 128;                 // within chunk
  const int z = blockIdx.z;
  const ushortT* A = phxT + (size_t)z * PPC + (size_t)tbase * CC;
  const ushortT* B = pgT + (size_t)z * PPC;
  ushortT* out = Ech + (size_t)z * TCH * PP;
  const int wi = (w & 1) * 64, wj = (w >> 1) * 64;
  const int lr = l & 15, lk = l >> 4;
  const int sr = l >> 3, scg = l & 7;

  f32x4 acc[4][4] = {};

  for (int k0 = 0; k0 < CC; k0 += 64) {
#pragma unroll
    for (int i = 0; i < 4; ++i) {
      int row = w * 32 + i * 8 + sr;
      int cs = scg ^ (row & 7);
      ld_g2l(A + (size_t)(i0 + row) * CC + k0 + cs * 8, (char*)At + (w * 4 + i) * 1024);
      ld_g2l(B + (size_t)(j0 + row) * CC + k0 + cs * 8, (char*)Bt + (w * 4 + i) * 1024);
    }
    __syncthreads();
#pragma unroll
    for (int ks = 0; ks < 2; ++ks) {
      short8 af[4], bfv[4];
      const int cc = ks * 4 + lk;
#pragma unroll
      for (int tt = 0; tt < 4; ++tt) {
        int row = wi + tt * 16 + lr;
        af[tt] = *(const short8*)((const char*)At + row * 128 + ((cc ^ (row & 7)) * 16));
      }
#pragma unroll
      for (int ss = 0; ss < 4; ++ss) {
        int row = wj + ss * 16 + lr;
        bfv[ss] = *(const short8*)((const char*)Bt + row * 128 + ((cc ^ (row & 7)) * 16));
      }
#pragma unroll
      for (int tt = 0; tt < 4; ++tt)
#pragma unroll
        for (int ss = 0; ss < 4; ++ss)
          acc[tt][ss] = __builtin_amdgcn_mfma_f32_16x16x32_bf16(af[tt], bfv[ss], acc[tt][ss], 0, 0, 0);
    }
    __syncthreads();
  }
  const int r4 = (l >> 4) * 4;
  // per-row partial stats over this block's 128 cols (reads acc regs only)
  const int jh = w >> 1;
  const int rbase = (w & 1) * 64;
#pragma unroll
  for (int tt = 0; tt < 4; ++tt)
#pragma unroll
    for (int r = 0; r < 4; ++r) {
      float mx = fmaxf(fmaxf(acc[tt][0][r], acc[tt][1][r]),
                       fmaxf(acc[tt][2][r], acc[tt][3][r]));
#pragma unroll
      for (int d = 1; d < 16; d <<= 1) mx = fmaxf(mx, __shfl_xor(mx, d));
      float sx = __expf(acc[tt][0][r] - mx) + __expf(acc[tt][1][r] - mx) +
                 __expf(acc[tt][2][r] - mx) + __expf(acc[tt][3][r] - mx);
#pragma unroll
      for (int d = 1; d < 16; d <<= 1) sx += __shfl_xor(sx, d);
      if (lr == 0) {
        int row = rbase + tt * 16 + r4 + r;
        Sm[row][jh] = mx;
        Ss[row][jh] = sx;
      }
    }
  // transpose-stage E tile into LDS (bf16)
  ushortT (*Tr)[136] = (ushortT(*)[136])smem;
#pragma unroll
  for (int tt = 0; tt < 4; ++tt)
#pragma unroll
    for (int r = 0; r < 4; ++r) {
      int row = wi + tt * 16 + r4 + r;
#pragma unroll
      for (int ss = 0; ss < 4; ++ss)
        Tr[row][wj + ss * 16 + lr] = f2bf(acc[tt][ss][r]);
    }
  __syncthreads();
  if (tid < 128) {
    float m0 = Sm[tid][0], m1 = Sm[tid][1];
    float m = fmaxf(m0, m1);
    float s = Ss[tid][0] * __expf(m0 - m) + Ss[tid][1] * __expf(m1 - m);
    size_t o = (((size_t)z * TCH + i0 + tid) * NJT + blockIdx.x) * 2;
    Estat[o] = m;
    Estat[o + 1] = s;
  }
#pragma unroll
  for (int q = 0; q < 8; ++q) {
    int chunk = q * 256 + tid;
    int row = chunk >> 4, cg = chunk & 15;
    short8 v = *(const short8*)&Tr[row][cg * 8];
    *(short8*)&out[(size_t)(i0 + row) * PP + j0 + cg * 8] = v;
  }
}

// ---------------------------------------------------------------------------
// exp pass (fused combine): row bf16 E -> bf16 P in place.
// grid NN*TCH blocks; Estat[row][NJT][2] reduced by first wave.
// ---------------------------------------------------------------------------
__global__ __launch_bounds__(256) void k_exp(ushortT* __restrict__ Ech,
                                             const float* __restrict__ Estat) {
  __shared__ float mzs[2];
  const int tid = threadIdx.x;
  ushortT* R = Ech + (size_t)blockIdx.x * PP;
  if (tid < 64) {
    float m = -INFINITY, s = 0.f;
    if (tid < NJT) {
      const float* p = Estat + ((size_t)blockIdx.x * NJT + tid) * 2;
      m = p[0];
      s = p[1];
    }
    float M = m;
#pragma unroll
    for (int d = 1; d < 64; d <<= 1) M = fmaxf(M, __shfl_xor(M, d));
    float t = s * __expf(m - M);
#pragma unroll
    for (int d = 1; d < 64; d <<= 1) t += __shfl_xor(t, d);
    if (tid == 0) { mzs[0] = M; mzs[1] = 1.0f / t; }
  }
  __syncthreads();
  const float m = mzs[0], rz = mzs[1];
  const int NCH = PP / 8;   // 784
  for (int i = tid; i < NCH; i += 256) {
    short8 v = *(const short8*)&R[i * 8];
    short8 o;
#pragma unroll
    for (int j = 0; j < 8; ++j)
      o[j] = (short)f2bf(__expf(bf2f((ushortT)v[j]) - m) * rz);
    *(short8*)&R[i * 8] = o;
  }
}

// ---------------------------------------------------------------------------
// me partial: mePart[ks][z][c][tl] (bf16) = sum_{s in ks-range} phm[c,s]*P[tl,s]
// 128c x 64t tile, BK=64. grid (TCH/64, CC/128, NN*KSP).
// Epilogue: LDS transpose -> coalesced 16B stores.
// ---------------------------------------------------------------------------
__global__ __launch_bounds__(256) void k_me(const ushortT* __restrict__ phmB,
                                            const ushortT* __restrict__ Ech,
                                            ushortT* __restrict__ mePart) {
  __shared__ __align__(16) ushortT smem[12288];   // At 16KB + Bt 8KB; epi 128x72
  ushortT* At = smem;          // phm [c][k]
  ushortT* Bt = smem + 8192;   // P   [t][k]
  const int tid = threadIdx.x;
  const int l = tid & 63, w = tid >> 6;
  const int tl0 = blockIdx.x * 64;
  const int c0 = blockIdx.y * 128;
  const int bz = blockIdx.z;
  const int z = bz / KSP, ks = bz % KSP;
  const size_t nb = (size_t)z * PPC;
  const ushortT* Pb = Ech + (size_t)z * TCH * PP;
  const int wc = (w & 1) * 64, wt = (w >> 1) * 32;
  const int lr = l & 15, lk = l >> 4;
  const int sr = l >> 3, scg = l & 7;

  f32x4 acc[4][2] = {};

  const int sBeg = ks * (PP / KSP);        // 896 each
  const int sEnd = sBeg + PP / KSP;
  for (int s0 = sBeg; s0 < sEnd; s0 += 64) {
#pragma unroll
    for (int i = 0; i < 4; ++i) {
      int row = w * 32 + i * 8 + sr;
      int cs = scg ^ (row & 7);
      ld_g2l(phmB + nb + (size_t)(c0 + row) * PP + s0 + cs * 8,
             (char*)At + (w * 4 + i) * 1024);
    }
#pragma unroll
    for (int i = 0; i < 2; ++i) {
      int row = w * 16 + i * 8 + sr;
      int cs = scg ^ (row & 7);
      ld_g2l(Pb + (size_t)(tl0 + row) * PP + s0 + cs * 8,
             (char*)Bt + (w * 2 + i) * 1024);
    }
    __syncthreads();
#pragma unroll
    for (int kk = 0; kk < 2; ++kk) {
      short8 af[4], bfv[2];
      const int cc = kk * 4 + lk;
#pragma unroll
      for (int ct = 0; ct < 4; ++ct) {
        int row = wc + ct * 16 + lr;
        af[ct] = *(const short8*)((const char*)At + row * 128 + ((cc ^ (row & 7)) * 16));
      }
#pragma unroll
      for (int tt = 0; tt < 2; ++tt) {
        int row = wt + tt * 16 + lr;
        bfv[tt] = *(const short8*)((const char*)Bt + row * 128 + ((cc ^ (row & 7)) * 16));
      }
#pragma unroll
      for (int ct = 0; ct < 4; ++ct)
#pragma unroll
        for (int tt = 0; tt < 2; ++tt)
          acc[ct][tt] = __builtin_amdgcn_mfma_f32_16x16x32_bf16(af[ct], bfv[tt], acc[ct][tt], 0, 0, 0);
    }
    __syncthreads();
  }
  const int r4 = (l >> 4) * 4;
  ushortT (*Tr)[72] = (ushortT(*)[72])smem;
#pragma unroll
  for (int ct = 0; ct < 4; ++ct)
#pragma unroll
    for (int r = 0; r < 4; ++r) {
      int row = wc + ct * 16 + r4 + r;
#pragma unroll
      for (int tt = 0; tt < 2; ++tt)
        Tr[row][wt + tt * 16 + lr] = f2bf(acc[ct][tt][r]);
    }
  __syncthreads();
  ushortT* out = mePart + ((size_t)(ks * NN + z) * CC) * TCH;
#pragma unroll
  for (int q = 0; q < 4; ++q) {
    int chunk = q * 256 + tid;        // 1024 chunks of 8 ushorts
    int row = chunk >> 3, cg = chunk & 7;
    short8 v = *(const short8*)&Tr[row][cg * 8];
    *(short8*)&out[(size_t)(c0 + row) * TCH + tl0 + cg * 8] = v;
  }
}

// ---------------------------------------------------------------------------
// meb[z][c][tbase+tl] (bf16) = sum over KSP partials
// ---------------------------------------------------------------------------
__global__ __launch_bounds__(256) void k_meadd(const ushortT* __restrict__ mePart,
                                               ushortT* __restrict__ meb, int tbase) {
  const int idx = (blockIdx.x * 256 + threadIdx.x) * 4;   // over NN*CC*TCH
  const int tl = idx % TCH;
  const int c = (idx / TCH) % CC;
  const int z = idx / (TCH * CC);
  float s0 = 0.f, s1 = 0.f, s2 = 0.f, s3 = 0.f;
#pragma unroll
  for (int ks = 0; ks < KSP; ++ks) {
    const size_t o = (((size_t)(ks * NN + z) * CC) + c) * TCH + tl;
    ushort4 a = *(const ushort4*)&mePart[o];
    s0 += bf2f(a.x); s1 += bf2f(a.y); s2 += bf2f(a.z); s3 += bf2f(a.w);
  }
  ushort4 v;
  v.x = f2bf(s0); v.y = f2bf(s1); v.z = f2bf(s2); v.w = f2bf(s3);
  *(ushort4*)&meb[((size_t)z * CC + c) * PP + tbase + tl] = v;
}

// ---------------------------------------------------------------------------
// softmax stats of bf16 me rows (per n,c)
// ---------------------------------------------------------------------------
__global__ __launch_bounds__(256) void k_soft2(const ushortT* __restrict__ me,
                                               float* __restrict__ m2,
                                               float* __restrict__ Z2) {
  __shared__ float red[256];
  const ushortT* row = me + (size_t)blockIdx.x * PP;
  const int tid = threadIdx.x;
  const int NCH = PP / 8;
  float m = -INFINITY;
  for (int i = tid; i < NCH; i += 256) {
    short8 v = *(const short8*)&row[i * 8];
#pragma unroll
    for (int j = 0; j < 8; ++j) m = fmaxf(m, bf2f((ushortT)v[j]));
  }
  red[tid] = m;
  __syncthreads();
  for (int s = 128; s > 0; s >>= 1) {
    if (tid < s) red[tid] = fmaxf(red[tid], red[tid + s]);
    __syncthreads();
  }
  m = red[0];
  __syncthreads();
  float zz = 0.f;
  for (int i = tid; i < NCH; i += 256) {
    short8 v = *(const short8*)&row[i * 8];
#pragma unroll
    for (int j = 0; j < 8; ++j) zz += __expf(bf2f((ushortT)v[j]) - m);
  }
  red[tid] = zz;
  __syncthreads();
  for (int s = 128; s > 0; s >>= 1) {
    if (tid < s) red[tid] += red[tid + s];
    __syncthreads();
  }
  if (tid == 0) { m2[blockIdx.x] = m; Z2[blockIdx.x] = red[0]; }
}

// ---------------------------------------------------------------------------
// BatchNorm stats per channel over (N, THW) from bf16 wz
// ---------------------------------------------------------------------------
__global__ __launch_bounds__(256) void k_bnstat(const ushortT* __restrict__ wz,
                                                float* __restrict__ mu,
                                                float* __restrict__ rinv) {
  __shared__ float rs[256];
  __shared__ float rq[256];
  const int c = blockIdx.x;
  const int tid = threadIdx.x;
  const int NCH = PP / 8;
  float s = 0.f, q = 0.f;
  for (int n = 0; n < NN; ++n) {
    const ushortT* rowp = wz + (size_t)n * CC * PP + (size_t)c * PP;
    for (int i = tid; i < NCH; i += 256) {
      short8 v = *(const short8*)&rowp[i * 8];
#pragma unroll
      for (int j = 0; j < 8; ++j) {
        float f = bf2f((ushortT)v[j]);
        s += f;
        q += f * f;
      }
    }
  }
  rs[tid] = s; rq[tid] = q;
  __syncthreads();
  for (int st = 128; st > 0; st >>= 1) {
    if (tid < st) { rs[tid] += rs[tid + st]; rq[tid] += rq[tid + st]; }
    __syncthreads();
  }
  if (tid == 0) {
    const float inv_n = 1.0f / (float)(NN * PP);
    float mean = rs[0] * inv_n;
    float var = rq[0] * inv_n - mean * mean;
    mu[c] = mean;
    rinv[c] = rsqrtf(var + 1e-5f);
  }
}

__global__ __launch_bounds__(256) void k_final(const ushortT* __restrict__ pmB,
                                               const ushortT* __restrict__ me,
                                               const ushortT* __restrict__ wz,
                                               const float* __restrict__ m2,
                                               const float* __restrict__ Z2,
                                               const float* __restrict__ mu,
                                               const float* __restrict__ rinv,
                                               const float* __restrict__ bnw,
                                               const float* __restrict__ bnb,
                                               const float* __restrict__ gamma,
                                               float* __restrict__ out) {
  const int e4 = blockIdx.x * 256 + threadIdx.x;
  const size_t e = (size_t)e4 * 4;
  const int nc = (int)(e / PP);
  const int c = nc & (CC - 1);
  const float m = m2[nc];
  const float rz = 1.0f / Z2[nc];
  const float mub = mu[c];
  const float ri = rinv[c] * bnw[c];
  const float bb = bnb[c];
  const float g = gamma[0];
  ushort4 pv = *(const ushort4*)&pmB[e];
  ushort4 mev = *(const ushort4*)&me[e];
  ushort4 wzv = *(const ushort4*)&wz[e];
  float4 o;
  o.x = g * bf2f(pv.x) * (__expf(bf2f(mev.x) - m) * rz) + (bf2f(wzv.x) - mub) * ri + bb;
  o.y = g * bf2f(pv.y) * (__expf(bf2f(mev.y) - m) * rz) + (bf2f(wzv.y) - mub) * ri + bb;
  o.z = g * bf2f(pv.z) * (__expf(bf2f(mev.z) - m) * rz) + (bf2f(wzv.z) - mub) * ri + bb;
  o.w = g * bf2f(pv.w) * (__expf(bf2f(mev.w) - m) * rz) + (bf2f(wzv.w) - mub) * ri + bb;
  *(float4*)&out[e] = o;
}

// ---------------------------------------------------------------------------
extern "C" void kernel_launch(void* const* d_in, const int* in_sizes, int n_in,
                              void* d_out, int out_size, void* d_ws, size_t ws_size,
                              hipStream_t stream) {
  (void)in_sizes; (void)n_in; (void)out_size; (void)ws_size;
  const float* x    = (const float*)d_in[0];
  const float* mask = (const float*)d_in[1];
  const float* Wh   = (const float*)d_in[2];
  const float* bh   = (const float*)d_in[3];
  const float* Wg   = (const float*)d_in[4];
  const float* bg   = (const float*)d_in[5];
  const float* Wm   = (const float*)d_in[6];
  const float* bm   = (const float*)d_in[7];
  const float* Wz   = (const float*)d_in[8];
  const float* bz   = (const float*)d_in[9];
  const float* bnw  = (const float*)d_in[10];
  const float* bnb  = (const float*)d_in[11];
  const float* gam  = (const float*)d_in[12];

  // ---- workspace layout (~144 MB) ----
  ushortT* wzb  = (ushortT*)d_ws;                // bf16 [n][c][p]
  ushortT* meb  = wzb + NCP;                     // bf16 [n][c][t]
  ushortT* pmB  = meb + NCP;                     // bf16 [n][c][p]
  ushortT* phxT = pmB + NCP;                     // bf16 [n][t][c]
  ushortT* pgT  = phxT + NCP;                    // bf16 [n][s][c]
  ushortT* phmB = pgT + NCP;                     // bf16 [n][c][s]
  ushortT* Wbf  = phmB + NCP;                    // 4 x 512x512 bf16
  ushortT* Whbf = Wbf;
  ushortT* Wgbf = Wbf + 1 * CC * CC;
  ushortT* Wmbf = Wbf + 2 * CC * CC;
  ushortT* Wzbf = Wbf + 3 * CC * CC;
  float* m2    = (float*)(Wbf + 4 * CC * CC);
  float* Z2    = m2 + NN * CC;
  float* mu    = Z2 + NN * CC;
  float* rin   = mu + CC;
  float* Estat = rin + CC;                       // NN*TCH*NJT*2  ~0.7 MB
  float* region = Estat + (size_t)NN * TCH * NJT * 2 + 4;
  ushortT* xT    = (ushortT*)region;             // overlay (conv phase) 25.7 MB
  ushortT* maskT = xT + NCP;
  ushortT* Ech    = (ushortT*)region;            // bf16 [n][TCH][PP]  22.5 MB
  ushortT* mePart = Ech + (size_t)NN * TCH * PP; // bf16 [KSP][n][c][TCH] 12.85 MB

  // ---- casts ----
  k_cast4<<<dim3(256, 4), 256, 0, stream>>>(Wh, Wg, Wm, Wz, Wbf);
  dim3 gct(PP / 32, CC / 32, NN);
  k_castT<<<gct, dim3(32, 8), 0, stream>>>(x, xT);
  k_castT<<<gct, dim3(32, 8), 0, stream>>>(mask, maskT);

  // ---- 1x1 convs as MFMA BT-GEMMs ----
  dim3 gPc(CC / 128, PP / 128, NN);   // out [p][co]
  k_bgemm<0><<<gPc, 256, 0, stream>>>(xT, Whbf, bh, phxT, CC, PPC, 0, PPC, CC);
  k_bgemm<0><<<gPc, 256, 0, stream>>>(xT, Wgbf, bg, pgT, CC, PPC, 0, PPC, CC);
  dim3 gCp(PP / 128, CC / 128, NN);   // out [co][p]
  k_bgemm<1><<<gCp, 256, 0, stream>>>(Whbf, maskT, bh, phmB, CC, 0, PPC, PPC, PP);
  k_bgemm<1><<<gCp, 256, 0, stream>>>(Wmbf, xT, bm, pmB, CC, 0, PPC, PPC, PP);
  k_bgemm<1><<<gCp, 256, 0, stream>>>(Wzbf, xT, bz, wzb, CC, 0, PPC, PPC, PP);

  // ---- attention: chunked energy(+stats) -> exp(+combine) -> me -> add ----
  for (int ch = 0; ch < NCHK; ++ch) {
    const int tbase = ch * TCH;
    dim3 gE(NJT, TCH / 128, NN);
    k_energy<<<gE, 256, 0, stream>>>(phxT, pgT, Ech, Estat, tbase);
    k_exp<<<NN * TCH, 256, 0, stream>>>(Ech, Estat);
    dim3 gM(TCH / 64, CC / 128, NN * KSP);
    k_me<<<gM, 256, 0, stream>>>(phmB, Ech, mePart);
    k_meadd<<<NN * CC * TCH / 1024, 256, 0, stream>>>(mePart, meb, tbase);
  }

  // ---- tails ----
  k_soft2<<<NN * CC, 256, 0, stream>>>(meb, m2, Z2);
  k_bnstat<<<CC, 256, 0, stream>>>(wzb, mu, rin);
  const int total4 = (int)(NCP / 4);
  k_final<<<total4 / 256, 256, 0, stream>>>(pmB, meb, wzb, m2, Z2, mu, rin,
                                            bnw, bnb, gam, (float*)d_out);
}